// Round 18
// baseline (28.249 us; speedup 1.0000x reference)
//
#include <hip/hip_runtime.h>
#include <math.h>

// B=2, N=512, DIM=3, C_IN=64, C_OUT=64
// ws layout (floats): s[1024] | gm8[131072] | flag[128]
#define WS_S    0
#define WS_GM8  1024
#define WS_FLAG (1024 + 131072)

typedef unsigned int u32;
typedef float f32x2 __attribute__((ext_vector_type(2)));

static __device__ __forceinline__ u32 bf16b(float x) {
    u32 u = __builtin_bit_cast(u32, x);
    return (u + 0x7FFFu + ((u >> 16) & 1u)) >> 16;   // RNE to bf16
}
static __device__ __forceinline__ float blo(u32 b) {   // low bf16 -> f32
    return __builtin_bit_cast(float, b << 16);
}
static __device__ __forceinline__ float bhi(u32 b) {   // high bf16 -> f32
    return __builtin_bit_cast(float, b & 0xFFFF0000u);
}

// ---------------------------------------------------------------------------
// Single fused kernel, grid 384 x 1024 (58KB LDS -> 2 blocks/CU, 2048 thr/CU:
// ALL 384 blocks co-resident in any dispatch order -> flag handshake safe).
//
// bx < 128 (PREP, dispatched first): wave wv<8 handles bj = bx*8+wv:
//   s[bj] = sum_c ||geom[bj,:,c]||*norm_w[c] + norm_b
//   gm8[bj][co] = uint2{bf16(a0)|bf16(a1)<<16, bf16(a2)<<16}
//   then: syncthreads, threadfence, release-store flag[bx]=1.
//
// bx >= 128 (MAIN): block = (b, i-quad) x FULL j; 16 waves = 32-j chunks x
// 4 i; lane = co. Pack phase is s-INDEPENDENT (ae = a*e2) so it overlaps
// prep; then 128 lanes acquire-spin on flag[0..128); then R16 consume with
// bej = fmaf(al, s_j, be):  w = max(al*ae + av*bej, 0)
//   acc_d += w * (gm_d + r_d*t64)        (pk_fma on d0,d1)
// Exclusive output: 2-phase LDS reduce (8+8 waves), direct store. No
// atomics, no out-zeroing.
//
// Replay idempotence: flags stay 1 -> replays skip the spin; concurrent
// prep rewrites of gm8/s are byte-identical so any read interleaving is
// correct. First call: ws poisoned 0xAA != 1 -> real spin.
// ---------------------------------------------------------------------------
__global__ __launch_bounds__(1024) void fused_kernel(
    const float* __restrict__ geom,    // [1024,3,64]
    const float* __restrict__ adj,     // [1024,512]
    const float* __restrict__ rel,     // [1024,512,3]
    const float* __restrict__ emb,     // [1024,512]
    const float* __restrict__ theta,   // [65,64]
    const float* __restrict__ norm_w,  // [65]
    const float* __restrict__ norm_b,  // [1]
    const float* __restrict__ alpha,   // [64]
    const float* __restrict__ beta,    // [64]
    float* __restrict__ s_arr,         // ws [1024]
    uint2* __restrict__ gm8,           // ws [1024,64]
    u32* __restrict__ flag,            // ws [128]
    float* __restrict__ out)           // [1024,192]
{
    const int bx   = blockIdx.x;       // 0..383
    const int tid  = threadIdx.x;      // 0..1023
    const int lane = tid & 63;
    const int wv   = tid >> 6;         // 0..15

    __shared__ char smem[59392];                         // 58 KB
    uint4 (*pk_l)[512] = (uint4(*)[512])smem;            // 32 KB [il][j]
    float (*red)[768]  = (float(*)[768])(smem + 32768);  // 24 KB
    float* s_l         = (float*)(smem + 32768 + 24576); // 2 KB
    float (*g)[192]    = (float(*)[192])smem;            // prep view: 6 KB

    // ================= PREP role =================
    if (bx < 128) {
        if (wv < 8) {
            const int bj = bx * 8 + wv;
            float* gw = g[wv];                 // per-wave private region
            const float* gb = geom + (size_t)bj * 192;
            gw[lane]       = gb[lane];
            gw[lane + 64]  = gb[lane + 64];
            gw[lane + 128] = gb[lane + 128];
            {
                float g0 = gw[lane], g1 = gw[64 + lane], g2 = gw[128 + lane];
                float t = sqrtf(g0 * g0 + g1 * g1 + g2 * g2) * norm_w[lane];
                for (int off = 32; off > 0; off >>= 1) t += __shfl_down(t, off);
                if (lane == 0) s_arr[bj] = t + norm_b[0];
            }
            float a0 = 0.f, a1 = 0.f, a2 = 0.f;
            for (int c = 0; c < 64; ++c) {
                float th = theta[c * 64 + lane];
                a0 = fmaf(gw[c],       th, a0);
                a1 = fmaf(gw[64 + c],  th, a1);
                a2 = fmaf(gw[128 + c], th, a2);
            }
            uint2 w;
            w.x = bf16b(a0) | (bf16b(a1) << 16);
            w.y = bf16b(a2) << 16;
            gm8[(size_t)bj * 64 + lane] = w;
        }
        __syncthreads();
        if (tid == 0) {
            __threadfence();
            __hip_atomic_store(&flag[bx], 1u, __ATOMIC_RELEASE,
                               __HIP_MEMORY_SCOPE_AGENT);
        }
        return;
    }

    // ================= MAIN role =================
    const int mx  = bx - 128;          // 0..255
    const int b   = mx >> 7;
    const int bi0 = b * 512 + (mx & 127) * 4;

    // ---- pack (s-independent; overlaps prep) ----
    {
        const float nw64 = norm_w[64];
        #pragma unroll
        for (int u = 0; u < 2; ++u) {
            int t  = tid + u * 1024;       // 0..2047
            int il = t >> 9;               // 0..3
            int j  = t & 511;
            size_t p = (size_t)(bi0 + il) * 512 + j;
            const float* rp = rel + p * 3;
            float r0 = rp[0], r1 = rp[1], r2 = rp[2];
            float a  = adj[p];
            float e2 = fmaf(nw64, sqrtf(r0 * r0 + r1 * r1 + r2 * r2), emb[p]);
            uint4 q;
            q.x = __builtin_bit_cast(u32, a * e2);   // ae
            q.y = __builtin_bit_cast(u32, a);        // av
            q.z = bf16b(r0) | (bf16b(r1) << 16);
            q.w = bf16b(r2) << 16;
            pk_l[il][j] = q;
        }
    }

    // ---- wait for prep ----
    if (tid < 128) {
        while (__hip_atomic_load(&flag[tid], __ATOMIC_ACQUIRE,
                                 __HIP_MEMORY_SCOPE_AGENT) != 1u) {}
    }
    __syncthreads();
    if (tid < 512) s_l[tid] = s_arr[b * 512 + tid];
    __syncthreads();

    const float al  = alpha[lane];
    const float be  = beta[lane];
    const float t64 = theta[64 * 64 + lane];
    const f32x2 t64v = {t64, t64};

    const uint2* gmv = gm8 + (size_t)(b * 512 + wv * 32) * 64 + lane;

    f32x2 acc01[4];
    float acc2[4];
    #pragma unroll
    for (int il = 0; il < 4; ++il) { acc01[il] = (f32x2){0.f, 0.f}; acc2[il] = 0.f; }

    #pragma unroll 4
    for (int jj = 0; jj < 32; ++jj) {
        const int J = wv * 32 + jj;
        uint2 gw = gmv[(size_t)jj * 64];           // 8B coalesced
        const f32x2 g01 = {blo(gw.x), bhi(gw.x)};
        const float gz  = bhi(gw.y);
        const float bej = fmaf(al, s_l[J], be);    // s folded here
        #pragma unroll
        for (int il = 0; il < 4; ++il) {
            uint4 q = pk_l[il][J];                 // broadcast b128
            float ae = __builtin_bit_cast(float, q.x);
            float av = __builtin_bit_cast(float, q.y);
            f32x2 r01 = {blo(q.z), bhi(q.z)};
            float r2  = __builtin_bit_cast(float, q.w);
            float w  = fmaxf(fmaf(al, ae, av * bej), 0.f);
            f32x2 wv2 = {w, w};
            f32x2 t01 = __builtin_elementwise_fma(r01, t64v, g01);  // v_pk_fma
            acc01[il] = __builtin_elementwise_fma(wv2, t01, acc01[il]);
            acc2[il]  = fmaf(w, fmaf(r2, t64, gz), acc2[il]);
        }
    }

    // ---- 2-phase 16-wave reduce (lane-contiguous b32, conflict-free) ----
    __syncthreads();                   // pk_l reads done (red aliases nothing)
    float* rw = &red[wv & 7][lane];
    if (wv < 8) {
        #pragma unroll
        for (int il = 0; il < 4; ++il) {
            rw[il * 192]       = acc01[il].x;
            rw[il * 192 + 64]  = acc01[il].y;
            rw[il * 192 + 128] = acc2[il];
        }
    }
    __syncthreads();
    if (wv >= 8) {
        #pragma unroll
        for (int il = 0; il < 4; ++il) {
            rw[il * 192]       += acc01[il].x;
            rw[il * 192 + 64]  += acc01[il].y;
            rw[il * 192 + 128] += acc2[il];
        }
    }
    __syncthreads();

    if (tid < 768) {
        float v = 0.f;
        #pragma unroll
        for (int r8 = 0; r8 < 8; ++r8) v += red[r8][tid];
        int il = tid / 192, r = tid - il * 192;
        out[(size_t)(bi0 + il) * 192 + r] = v;   // exclusive, direct store
    }
}

extern "C" void kernel_launch(void* const* d_in, const int* in_sizes, int n_in,
                              void* d_out, int out_size, void* d_ws, size_t ws_size,
                              hipStream_t stream) {
    const float* geom   = (const float*)d_in[0];
    const float* adj    = (const float*)d_in[1];
    const float* rel    = (const float*)d_in[2];
    const float* emb    = (const float*)d_in[3];
    const float* theta  = (const float*)d_in[4];
    const float* norm_w = (const float*)d_in[5];
    const float* norm_b = (const float*)d_in[6];
    const float* alpha  = (const float*)d_in[7];
    const float* beta   = (const float*)d_in[8];
    float* out = (float*)d_out;

    float* ws   = (float*)d_ws;
    float* s    = ws + WS_S;
    uint2* gm8  = (uint2*)(ws + WS_GM8);
    u32*   flag = (u32*)(ws + WS_FLAG);

    fused_kernel<<<384, 1024, 0, stream>>>(geom, adj, rel, emb, theta, norm_w,
                                           norm_b, alpha, beta, s, gm8, flag, out);
}

// Round 19
// 21.689 us; speedup vs baseline: 1.3025x; 1.3025x over previous
//
#include <hip/hip_runtime.h>
#include <math.h>

// B=2, N=512, DIM=3, C_IN=64, C_OUT=64
// ws layout (floats): s[1024] | gm8[1024*128 (uint2 per co)]
#define WS_S   0
#define WS_GM8 1024

typedef unsigned int u32;
typedef float f32x2 __attribute__((ext_vector_type(2)));

static __device__ __forceinline__ u32 bf16b(float x) {
    u32 u = __builtin_bit_cast(u32, x);
    return (u + 0x7FFFu + ((u >> 16) & 1u)) >> 16;   // RNE to bf16
}
static __device__ __forceinline__ float blo(u32 b) {   // low bf16 -> f32
    return __builtin_bit_cast(float, b << 16);
}
static __device__ __forceinline__ float bhi(u32 b) {   // high bf16 -> f32
    return __builtin_bit_cast(float, b & 0xFFFF0000u);
}

// ---------------------------------------------------------------------------
// Prep, grid 512 x 256:
//  all bx:  zero out[bx*384 .. +384)
//  bx<256:  4 bj each:  s[bj] = sum_c ||geom[bj,:,c]||*norm_w[c] + norm_b
//           gm8[bj][co] = uint2{ bf16(a0)|bf16(a1)<<16, bf16(a2)<<16 }
// ---------------------------------------------------------------------------
__global__ __launch_bounds__(256) void prep_kernel(
    const float* __restrict__ geom,    // [1024,3,64]
    const float* __restrict__ theta,   // [65,64]
    const float* __restrict__ norm_w,  // [65]
    const float* __restrict__ norm_b,  // [1]
    float* __restrict__ s,             // [1024]
    uint2* __restrict__ gm8,           // [1024,64]
    float* __restrict__ out)           // [1024,192]
{
    const int bx  = blockIdx.x;
    const int tid = threadIdx.x;

    for (int k = tid; k < 384; k += 256)
        out[(size_t)bx * 384 + k] = 0.f;

    if (bx < 256) {
        const int sub  = tid >> 6;      // which of 4 bj
        const int lane = tid & 63;      // = c, and = co
        const int bj   = bx * 4 + sub;
        __shared__ float g[4][192];     // [d*64 + c]
        const float* gb = geom + (size_t)bj * 192;
        g[sub][lane]       = gb[lane];
        g[sub][lane + 64]  = gb[lane + 64];
        g[sub][lane + 128] = gb[lane + 128];
        __syncthreads();

        {
            float g0 = g[sub][lane], g1 = g[sub][64 + lane], g2 = g[sub][128 + lane];
            float t = sqrtf(g0 * g0 + g1 * g1 + g2 * g2) * norm_w[lane];
            for (int off = 32; off > 0; off >>= 1) t += __shfl_down(t, off);
            if (lane == 0) s[bj] = t + norm_b[0];
        }

        float a0 = 0.f, a1 = 0.f, a2 = 0.f;
        for (int c = 0; c < 64; ++c) {
            float th = theta[c * 64 + lane];
            a0 = fmaf(g[sub][c],       th, a0);
            a1 = fmaf(g[sub][64 + c],  th, a1);
            a2 = fmaf(g[sub][128 + c], th, a2);
        }
        uint2 w;
        w.x = bf16b(a0) | (bf16b(a1) << 16);
        w.y = bf16b(a2) << 16;
        gm8[(size_t)bj * 64 + lane] = w;
    }
}

// ---------------------------------------------------------------------------
// Main, grid 512 = (b*256 + iq*2 + jh), 512 thr = 8 waves (16 waves/CU).
// Block = (b, i-quad, j-half); wave = 32-j chunk x 4 i; lane = co.
// Per-pair operands packed in LDS i-major (lane-contiguous b128 writes,
// conflict-free; broadcast b128 reads). gm as bf16x3 uint2 (half L2 stream).
// (d0,d1) accumulate via v_pk_fma_f32. Two jh halves combine via atomicAdd
// into prep-zeroed out (2 commutative addends -> deterministic).
//   an = a*naf (s folded in pack);  w = relu(al*an + be*a)
//   acc_d += w * (gm_d + r_d*t64)
// ---------------------------------------------------------------------------
__global__ __launch_bounds__(512) void main_kernel(
    const float* __restrict__ adj,     // [1024,512]
    const float* __restrict__ rel,     // [1024,512,3]
    const float* __restrict__ emb,     // [1024,512]
    const float* __restrict__ s_arr,   // [1024]
    const uint2* __restrict__ gm8,     // [1024,64]
    const float* __restrict__ theta,   // [65,64]
    const float* __restrict__ norm_w,  // [65]
    const float* __restrict__ alpha,   // [64]
    const float* __restrict__ beta,    // [64]
    float* __restrict__ out)           // [1024,192]
{
    const int bx   = blockIdx.x;
    const int jh   = bx & 1;
    const int iq   = (bx >> 1) & 127;
    const int b    = bx >> 8;
    const int tid  = threadIdx.x;      // 0..511
    const int lane = tid & 63;         // co
    const int wv   = tid >> 6;         // 0..7
    const int bi0  = b * 512 + iq * 4;
    const int j0   = jh * 256;

    __shared__ uint4 pk_l[4][256];     // 16 KB, i-major
    __shared__ float red[8][768];      // 24 KB

    // ---- pack: t = il*256 + j, lane-contiguous b128 writes ----
    {
        const float nw64 = norm_w[64];
        #pragma unroll
        for (int u = 0; u < 2; ++u) {
            int t  = tid + u * 512;        // 0..1023
            int il = t >> 8;               // 0..3
            int j  = t & 255;
            size_t p = (size_t)(bi0 + il) * 512 + j0 + j;
            const float* rp = rel + p * 3;
            float r0 = rp[0], r1 = rp[1], r2 = rp[2];
            float a   = adj[p];
            float naf = s_arr[b * 512 + j0 + j]
                      + nw64 * sqrtf(r0 * r0 + r1 * r1 + r2 * r2) + emb[p];
            uint4 q;
            q.x = __builtin_bit_cast(u32, a * naf);
            q.y = __builtin_bit_cast(u32, a);
            q.z = bf16b(r0) | (bf16b(r1) << 16);
            q.w = bf16b(r2) << 16;
            pk_l[il][j] = q;
        }
    }
    __syncthreads();

    const float al  = alpha[lane];
    const float be  = beta[lane];
    const float t64 = theta[64 * 64 + lane];
    const f32x2 t64v = {t64, t64};

    const uint2* gmv = gm8 + (size_t)(b * 512 + j0 + wv * 32) * 64 + lane;

    f32x2 acc01[4];
    float acc2[4];
    #pragma unroll
    for (int il = 0; il < 4; ++il) { acc01[il] = (f32x2){0.f, 0.f}; acc2[il] = 0.f; }

    #pragma unroll 4
    for (int jj = 0; jj < 32; ++jj) {
        uint2 gw = gmv[(size_t)jj * 64];           // 8B coalesced
        const f32x2 g01 = {blo(gw.x), bhi(gw.x)};
        const float gz  = bhi(gw.y);
        #pragma unroll
        for (int il = 0; il < 4; ++il) {
            uint4 q = pk_l[il][wv * 32 + jj];      // broadcast b128
            float an = __builtin_bit_cast(float, q.x);
            float av = __builtin_bit_cast(float, q.y);
            f32x2 r01 = {blo(q.z), bhi(q.z)};
            float r2  = __builtin_bit_cast(float, q.w);
            float w  = fmaxf(fmaf(al, an, be * av), 0.f);
            f32x2 wv2 = {w, w};
            f32x2 t01 = __builtin_elementwise_fma(r01, t64v, g01);  // v_pk_fma
            acc01[il] = __builtin_elementwise_fma(wv2, t01, acc01[il]);
            acc2[il]  = fmaf(w, fmaf(r2, t64, gz), acc2[il]);
        }
    }

    // ---- 8-wave reduce (lane-contiguous b32, conflict-free) ----
    float* rw = &red[wv][lane];
    #pragma unroll
    for (int il = 0; il < 4; ++il) {
        rw[il * 192]       = acc01[il].x;
        rw[il * 192 + 64]  = acc01[il].y;
        rw[il * 192 + 128] = acc2[il];
    }
    __syncthreads();

    for (int k = tid; k < 768; k += 512) {
        float v = 0.f;
        #pragma unroll
        for (int w8 = 0; w8 < 8; ++w8) v += red[w8][k];
        int il = k / 192, r = k - il * 192;
        atomicAdd(&out[(size_t)(bi0 + il) * 192 + r], v);
    }
}

extern "C" void kernel_launch(void* const* d_in, const int* in_sizes, int n_in,
                              void* d_out, int out_size, void* d_ws, size_t ws_size,
                              hipStream_t stream) {
    const float* geom   = (const float*)d_in[0];
    const float* adj    = (const float*)d_in[1];
    const float* rel    = (const float*)d_in[2];
    const float* emb    = (const float*)d_in[3];
    const float* theta  = (const float*)d_in[4];
    const float* norm_w = (const float*)d_in[5];
    const float* norm_b = (const float*)d_in[6];
    const float* alpha  = (const float*)d_in[7];
    const float* beta   = (const float*)d_in[8];
    float* out = (float*)d_out;

    float* ws  = (float*)d_ws;
    float* s   = ws + WS_S;
    uint2* gm8 = (uint2*)(ws + WS_GM8);

    prep_kernel<<<512, 256, 0, stream>>>(geom, theta, norm_w, norm_b, s, gm8, out);
    main_kernel<<<512, 512, 0, stream>>>(adj, rel, emb, s, gm8, theta, norm_w,
                                         alpha, beta, out);
}